// Round 1
// baseline (301.103 us; speedup 1.0000x reference)
//
#include <hip/hip_runtime.h>
#include <hip/hip_fp16.h>
#include <math.h>

#define NPIX 262144   // 512*512
#define BATCH 4
#define RANK 8
#define CTXD 512
#define OUTF 210

// ---- workspace layout (float offsets) ----
#define XT_OFF   0      // xt[4][210] (840 floats)
#define BAR_IDX  1016   // uint spin-barrier counter (zeroed by k_ctx)
#define ACC_OFF  1024   // 8 replicas x 176 accumulators (gram[4][36], S[4][8])
#define REP      8
#define NACC     176
#define NBLK     512    // fused-kernel grid; all blocks must be co-resident

// ---------------- wave64 sum via DPP (result in lane 63) ---------------------
__device__ __forceinline__ float dpp_sum64(float x) {
  x += __int_as_float(__builtin_amdgcn_update_dpp(0, __float_as_int(x), 0x111, 0xf, 0xf, true)); // row_shr:1
  x += __int_as_float(__builtin_amdgcn_update_dpp(0, __float_as_int(x), 0x112, 0xf, 0xf, true)); // row_shr:2
  x += __int_as_float(__builtin_amdgcn_update_dpp(0, __float_as_int(x), 0x114, 0xf, 0xf, true)); // row_shr:4
  x += __int_as_float(__builtin_amdgcn_update_dpp(0, __float_as_int(x), 0x118, 0xf, 0xf, true)); // row_shr:8
  x += __int_as_float(__builtin_amdgcn_update_dpp(0, __float_as_int(x), 0x142, 0xf, 0xf, true)); // row_bcast:15
  x += __int_as_float(__builtin_amdgcn_update_dpp(0, __float_as_int(x), 0x143, 0xf, 0xf, true)); // row_bcast:31
  return x;
}

// ---------------- threefry2x32 (JAX original scheme, key=(0,42)) -------------
__device__ __forceinline__ void threefry2x32_pair(unsigned int x0, unsigned int x1,
                                                  unsigned int* o0, unsigned int* o1) {
  const unsigned int ks0 = 0u, ks1 = 42u, ks2 = 0x1BD11BF0u;
  x0 += ks0; x1 += ks1;
#define TF_R(rot) { x0 += x1; x1 = (x1 << rot) | (x1 >> (32 - rot)); x1 ^= x0; }
  TF_R(13) TF_R(15) TF_R(26) TF_R(6)
  x0 += ks1; x1 += ks2 + 1u;
  TF_R(17) TF_R(29) TF_R(16) TF_R(24)
  x0 += ks2; x1 += ks0 + 2u;
  TF_R(13) TF_R(15) TF_R(26) TF_R(6)
  x0 += ks0; x1 += ks1 + 3u;
  TF_R(17) TF_R(29) TF_R(16) TF_R(24)
  x0 += ks1; x1 += ks2 + 4u;
  TF_R(13) TF_R(15) TF_R(26) TF_R(6)
  x0 += ks2; x1 += ks0 + 5u;
#undef TF_R
  *o0 = x0; *o1 = x1;
}

// bits -> uniform(-1,1) -> sqrt(2)*erfinv. Giles polys TRUNCATED 9->5 terms:
// abs error <= 2.2e-3 (w<5) / 7.5e-3 (w>=5) in the normal sample; noise is
// scaled by ~2e-6, so worst-case output perturbation ~1.4e-7 << 1.05e-5 budget.
__device__ __forceinline__ float fast_normal(unsigned int bits) {
  unsigned int fb = (bits >> 9) | 0x3f800000u;
  float f = __uint_as_float(fb) - 1.0f;                 // [0,1)
  const float lo = -0.99999994039535522461f;            // nextafter(-1,0) f32
  float u = f * 2.0f + lo;
  u = fmaxf(u, lo);
  float w = -__logf(fmaf(-u, u, 1.0f));                 // -log(1-u^2)
  float q1 = w - 2.5f;
  float p1 = 0.00021858087f;
  p1 = fmaf(p1, q1, -0.00125372503f);
  p1 = fmaf(p1, q1, -0.00417768164f);
  p1 = fmaf(p1, q1, 0.246640727f);
  p1 = fmaf(p1, q1, 1.50140941f);
  float q2 = sqrtf(w) - 3.0f;
  float p2 = 0.00573950773f;
  p2 = fmaf(p2, q2, -0.0076224613f);
  p2 = fmaf(p2, q2, 0.00943887047f);
  p2 = fmaf(p2, q2, 1.00167406f);
  p2 = fmaf(p2, q2, 2.83297682f);
  float pr = (w < 5.0f) ? p1 : p2;
  return 1.4142135623730951f * pr * u;
}

// ---------------- K1: ctx MLP + accumulator/barrier zeroing ------------------
__global__ __launch_bounds__(256) void k_ctx(const float* __restrict__ x,
                                             const float* __restrict__ cw,
                                             const float* __restrict__ cb,
                                             float* __restrict__ ws) {
  // zero the REP*NACC atomic accumulators + the grid-barrier counter (kernel
  // boundary publishes these before k_fused's atomics touch them)
  int gi = blockIdx.x * 256 + threadIdx.x;
  if (gi < REP * NACC) ws[ACC_OFF + gi] = 0.f;
  if (gi == 0) ((unsigned int*)ws)[BAR_IDX] = 0u;

  int lane = threadIdx.x & 63, wv = threadIdx.x >> 6;
  int row = blockIdx.x * 4 + wv;            // 0..839 (grid=210 exactly covers)
  int b = row / OUTF, i = row - b * OUTF;
  const float* wrow = cw + i * CTXD;
  const float* xr = x + b * CTXD;
  float acc = 0.f;
#pragma unroll
  for (int u = 0; u < CTXD; u += 64)
    acc = fmaf(wrow[u + lane], xr[u + lane], acc);
  acc = dpp_sum64(acc);
  if (lane == 63) ws[XT_OFF + row] = acc + cb[i];
}

// ---------------- K2: fused wf + gram + grid barrier + stats + output --------
// Persistent-register fusion: each thread owns 2 adjacent pixels, computes
// wf[4][8][2] ONCE (fp32, stays in VGPRs across the barrier — the old 32 MiB
// fp16 wfs round trip is gone), generates its 64 noise normals during the
// BW-bound weights stream (threefry VALU hides under HBM latency), then after
// a device-scope spin barrier every block redundantly computes the tiny
// analytic-stats preamble and writes its own pixels.
// Co-residency: __launch_bounds__(256,2) caps VGPR at 256 -> >=2 blocks/CU,
// LDS ~7KB -> 512 blocks all resident; spin barrier cannot deadlock.
__global__ __launch_bounds__(256, 2) void k_fused(const float* __restrict__ wts,
                                                  float* __restrict__ ws,
                                                  float* __restrict__ out) {
  __shared__ float4 mods[32][3];   // [b*8+k][0]=A0,B0  [1]=A1,B1  [2]=biases
  __shared__ float gred[4][NACC];
  __shared__ float G[NACC];                  // [0:144) gram, [144:176) S
  __shared__ float n1[32], Ml[256], vv[32], scl[32], ca[4], wrl[BATCH][9];
  __shared__ float in2[32], mnv[32], sdv[32];

  const float* xt = ws + XT_OFF;
  int t = threadIdx.x;

  if (t < 96) {
    int bk = t / 3, part = t - bk * 3;
    int b = bk >> 3, k = bk & 7;
    const float* xb = xt + b * OUTF + 12 * k;
#define GATE(j) (xb[j] * tanhf(xb[105 + (j)]))
    float4 r;
    if (part < 2) {
      float c0 = GATE(2 * part) + 0.5f;
      float c1 = GATE(2 * part + 1);
      float s0 = GATE(8 + 2 * part) + 1.0f;
      float s1 = GATE(9 + 2 * part);
      float omc = 1.0f - c0;
      r.x = s0 * omc + s1 * c1;   // A_r
      r.y = s1 * omc - s0 * c1;   // A_i
      r.z = s0 * c0 - s1 * c1;    // B_r
      r.w = s1 * c0 + s0 * c1;    // B_i
    } else {
      r.x = GATE(4); r.y = GATE(5); r.z = GATE(6); r.w = GATE(7);
    }
#undef GATE
    mods[bk][part] = r;
  }
  __syncthreads();

  int tp = blockIdx.x * 256 + t;            // 0..131071, 2 adjacent pixels each
  const float4* w4 = (const float4*)wts;    // float4 = 2 complex px; 2^17 per page
  float wf[BATCH][RANK][2];
  __half2 nzA[16], nzB[16];                 // 64 noise normals, fp16-packed in regs
#pragma unroll
  for (int k = 0; k < RANK; ++k) {
    // ld[lerp][comp] = {px0.re, px0.im, px1.re, px1.im}
    float4 ld[2][2];
#pragma unroll
    for (int s = 0; s < 2; ++s)
#pragma unroll
      for (int comp = 0; comp < 2; ++comp)
        ld[s][comp] = w4[((k * 4 + s * 2 + comp) << 17) + tp];

    // noise threefry for bk=k and k+8, both pixels — pure VALU, scheduled by
    // the compiler into the global-load stall shadow (phase is BW-bound)
#pragma unroll
    for (int b2 = 0; b2 < 2; ++b2) {
      int bk = b2 * 8 + k;
      unsigned int i0 = ((unsigned int)bk << 18) + 2u * (unsigned int)tp;
      unsigned int ra0, ra1, rb0, rb1;
      threefry2x32_pair(i0,      i0 + 0x400000u, &ra0, &ra1);
      threefry2x32_pair(i0 + 1u, i0 + 0x400001u, &rb0, &rb1);
      nzA[bk] = __halves2half2(__float2half(fast_normal(ra0)), __float2half(fast_normal(rb0)));
      nzB[bk] = __halves2half2(__float2half(fast_normal(ra1)), __float2half(fast_normal(rb1)));
    }

#pragma unroll
    for (int b = 0; b < BATCH; ++b) {
      float4 P  = mods[b * 8 + k][0];
      float4 Q  = mods[b * 8 + k][1];
      float4 Bb = mods[b * 8 + k][2];
#pragma unroll
      for (int j = 0; j < 2; ++j) {
        float w0r = j ? ld[0][0].z : ld[0][0].x;
        float w0i = j ? ld[0][0].w : ld[0][0].y;
        float w1r = j ? ld[1][0].z : ld[1][0].x;
        float w1i = j ? ld[1][0].w : ld[1][0].y;
        float v0r = j ? ld[0][1].z : ld[0][1].x;
        float v0i = j ? ld[0][1].w : ld[0][1].y;
        float v1r = j ? ld[1][1].z : ld[1][1].x;
        float v1i = j ? ld[1][1].w : ld[1][1].y;
        float zr0 = fmaf(P.x, w0r, fmaf(-P.y, w0i, fmaf(P.z, w1r, fmaf(-P.w, w1i, Bb.x))));
        float zi0 = fmaf(P.y, w0r, fmaf( P.x, w0i, fmaf(P.w, w1r, fmaf( P.z, w1i, Bb.y))));
        float zr1 = fmaf(Q.x, v0r, fmaf(-Q.y, v0i, fmaf(Q.z, v1r, fmaf(-Q.w, v1i, Bb.z))));
        float zi1 = fmaf(Q.y, v0r, fmaf( Q.x, v0i, fmaf(Q.w, v1r, fmaf( Q.z, v1i, Bb.w))));
        float d2 = fmaxf(fmaf(zr1, zr1, zi1 * zi1), 1e-12f);
        float rn = __builtin_amdgcn_rsqf(d2);          // v_rsq_f32, ~1 ulp
        wf[b][k][j] = fmaf(zr0, zr1, zi0 * zi1) * rn;  // stays in registers
      }
    }
  }

  // reduce gram[4][36] (upper-tri incl diag) + S[4][8]; 2-px register pre-sum
  int lane = t & 63, wv = t >> 6;
#pragma unroll
  for (int b = 0; b < BATCH; ++b) {
    int idx = b * 36;
#pragma unroll
    for (int r = 0; r < RANK; ++r)
#pragma unroll
      for (int s2 = r; s2 < RANK; ++s2, ++idx) {
        float pr = dpp_sum64(fmaf(wf[b][r][0], wf[b][s2][0], wf[b][r][1] * wf[b][s2][1]));
        if (lane == 63) gred[wv][idx] = pr;
      }
  }
#pragma unroll
  for (int b = 0; b < BATCH; ++b)
#pragma unroll
    for (int k = 0; k < RANK; ++k) {
      float pr = dpp_sum64(wf[b][k][0] + wf[b][k][1]);
      if (lane == 63) gred[wv][144 + b * 8 + k] = pr;
    }
  __syncthreads();
  // 256 threads > NACC=176, but keep the stride loop (defensive)
  for (int i = t; i < NACC; i += 256) {
    float s = gred[0][i] + gred[1][i] + gred[2][i] + gred[3][i];
    // 8-way replicated accumulators: same-address contention /8
    atomicAdd(ws + ACC_OFF + (blockIdx.x & (REP - 1)) * NACC + i, s);
  }

  // ---- device-scope grid barrier (all NBLK blocks co-resident) ----
  // __syncthreads drains vmcnt -> this block's atomics are at the coherent
  // point; release fetch_add publishes, acquire spin + agent-scope loads below
  // observe all blocks' adds (per-XCD L2 is non-coherent: plain loads unsafe).
  __syncthreads();
  if (t == 0) {
    unsigned int* bar = (unsigned int*)ws + BAR_IDX;
    __hip_atomic_fetch_add(bar, 1u, __ATOMIC_ACQ_REL, __HIP_MEMORY_SCOPE_AGENT);
    while (__hip_atomic_load(bar, __ATOMIC_ACQUIRE, __HIP_MEMORY_SCOPE_AGENT) < (unsigned int)NBLK)
      __builtin_amdgcn_s_sleep(1);
  }
  __syncthreads();

  // ---- analytic stats (redundant per block; ~trivial ALU) ----
  if (t < NACC) {
    float s = 0.f;
#pragma unroll
    for (int rep = 0; rep < REP; ++rep)
      s += __hip_atomic_load(ws + ACC_OFF + rep * NACC + t,
                             __ATOMIC_RELAXED, __HIP_MEMORY_SCOPE_AGENT);
    G[t] = s;
  }
  if (t >= 192 && t < 192 + BATCH) {         // wr softmax (per-batch thread)
    int b = t - 192;
    float raw[9];
#pragma unroll
    for (int j = 0; j < 9; ++j)
      raw[j] = xt[b * OUTF + 96 + j] * tanhf(xt[b * OUTF + 201 + j]);
    raw[8] += 0.35355339059327373f;          // 1/sqrt(8)
    double ss = 0.0;
    for (int j = 0; j < 9; ++j) ss += (double)raw[j] * (double)raw[j];
    float n = fmaxf((float)sqrt(ss), 1e-12f);
    float y[9]; float m = -1e30f;
    for (int j = 0; j < 9; ++j) { y[j] = raw[j] / n; m = fmaxf(m, y[j]); }
    float e[9]; double se = 0.0;
    for (int j = 0; j < 9; ++j) { e[j] = expf(y[j] - m); se += (double)e[j]; }
    for (int j = 0; j < 9; ++j) wrl[b][j] = e[j] / (float)se;
  }
  __syncthreads();
  if (t < 32) {
    int b = t >> 3, k = t & 7;
    int di = k * 8 - (k * (k - 1)) / 2;
    n1[t] = fmaxf(sqrtf(G[b * 36 + di]), 1e-12f);
  }
  __syncthreads();
  {
    int b = t >> 6, k = (t >> 3) & 7, s = t & 7;
    float m;
    if (k == s) {
      m = 1.0f / n1[b * 8 + k];
    } else {
      int r0 = k < s ? k : s, s0 = k < s ? s : k;
      int gi = r0 * 8 - (r0 * (r0 - 1)) / 2 + (s0 - r0);
      float simv = G[b * 36 + gi] / (n1[b * 8 + k] * n1[b * 8 + s]);
      m = -0.0050507627227610544f * simv / n1[b * 8 + s];  // (0.1/sqrt(8))/7
    }
    Ml[t] = m;
  }
  __syncthreads();
  if (t < 32) {
    int b = t >> 3, k = t & 7;
    // sum = M.S ; sumsq = (M G M^T)_kk — exact linear algebra of the 2nd pass
    float sum = 0.f, sq = 0.f;
#pragma unroll
    for (int s = 0; s < 8; ++s) {
      float ms = Ml[b * 64 + k * 8 + s];
      sum = fmaf(ms, G[144 + b * 8 + s], sum);
#pragma unroll
      for (int u = 0; u < 8; ++u) {
        int r0 = s < u ? s : u, s0 = s < u ? u : s;
        int gi = r0 * 8 - (r0 * (r0 - 1)) / 2 + (s0 - r0);
        sq = fmaf(ms * Ml[b * 64 + k * 8 + u], G[b * 36 + gi], sq);
      }
    }
    float n2 = fmaxf(sqrtf(fmaxf(sq, 0.f)), 1e-12f);
    float mean = sum / n2 * (1.0f / NPIX);
    float sy2 = sq / (n2 * n2);
    float var = (sy2 - (float)NPIX * mean * mean) * (1.0f / (float)(NPIX - 1));
    var = fmaxf(var, 0.f);
    float sd = fmaxf(sqrtf(var), 1e-12f);
    in2[t] = 1.f / n2; mnv[t] = mean; sdv[t] = sd;
  }
  __syncthreads();
  if (t < 32) {
    int b = t >> 3, s = t & 7;
    float acc = 0.f;
#pragma unroll
    for (int k = 0; k < 8; ++k)
      acc += wrl[b][k] * Ml[b * 64 + k * 8 + s] * in2[b * 8 + k];
    vv[t] = acc;
    scl[t] = wrl[b][s] * 0.01f * sdv[t];
  }
  if (t < BATCH) {
    float a = 0.f;
#pragma unroll
    for (int k = 0; k < 8; ++k) a += wrl[t][k] * 0.01f * mnv[t * 8 + k];
    ca[t] = a;
  }
  __syncthreads();

  // ---- output: fp32 wf straight from registers + register-held noise ----
  float o0[4], o1[4];
#pragma unroll
  for (int b = 0; b < 4; ++b) { o0[b] = ca[b]; o1[b] = ca[b]; }
#pragma unroll
  for (int b = 0; b < 4; ++b)
#pragma unroll
    for (int s = 0; s < 8; ++s) {
      float v = vv[b * 8 + s];
      o0[b] = fmaf(v, wf[b][s][0], o0[b]);
      o1[b] = fmaf(v, wf[b][s][1], o1[b]);
    }
#pragma unroll
  for (int b2 = 0; b2 < 2; ++b2)
#pragma unroll
    for (int k = 0; k < 8; ++k) {
      int bk = b2 * 8 + k;
      o0[b2]     = fmaf(scl[b2 * 8 + k],       __low2float (nzA[bk]), o0[b2]);
      o1[b2]     = fmaf(scl[b2 * 8 + k],       __high2float(nzA[bk]), o1[b2]);
      o0[b2 + 2] = fmaf(scl[(b2 + 2) * 8 + k], __low2float (nzB[bk]), o0[b2 + 2]);
      o1[b2 + 2] = fmaf(scl[(b2 + 2) * 8 + k], __high2float(nzB[bk]), o1[b2 + 2]);
    }
#pragma unroll
  for (int b = 0; b < 4; ++b)
    ((float2*)out)[(b << 17) + tp] = make_float2(o0[b], o1[b]);  // coalesced 8B
}

extern "C" void kernel_launch(void* const* d_in, const int* in_sizes, int n_in,
                              void* d_out, int out_size, void* d_ws, size_t ws_size,
                              hipStream_t stream) {
  const float* x   = (const float*)d_in[0];
  const float* cw  = (const float*)d_in[1];
  const float* cb  = (const float*)d_in[2];
  const float* wts = (const float*)d_in[3];
  float* out = (float*)d_out;
  float* ws  = (float*)d_ws;

  k_ctx  <<<210,  256, 0, stream>>>(x, cw, cb, ws);   // xt + zero ACC/barrier
  k_fused<<<NBLK, 256, 0, stream>>>(wts, ws, out);    // everything else
}

// Round 4
// 295.562 us; speedup vs baseline: 1.0187x; 1.0187x over previous
//
#include <hip/hip_runtime.h>
#include <hip/hip_fp16.h>
#include <math.h>

#define NPIX 262144   // 512*512
#define BATCH 4
#define RANK 8
#define CTXD 512
#define OUTF 210

// ---- workspace layout (float offsets) ----
#define XT_OFF   0      // xt[4][210] (840 floats)
#define BAR_IDX  1016   // uint spin-barrier counter (zeroed by k_ctx)
#define ACC_OFF  1024   // 8 replicas x 176 accumulators (gram[4][36], S[4][8])
#define REP      8
#define NACC     176
#define NBLK     512    // fused-kernel grid

// ---------------- wave64 sum via DPP (result in lane 63) ---------------------
__device__ __forceinline__ float dpp_sum64(float x) {
  x += __int_as_float(__builtin_amdgcn_update_dpp(0, __float_as_int(x), 0x111, 0xf, 0xf, true)); // row_shr:1
  x += __int_as_float(__builtin_amdgcn_update_dpp(0, __float_as_int(x), 0x112, 0xf, 0xf, true)); // row_shr:2
  x += __int_as_float(__builtin_amdgcn_update_dpp(0, __float_as_int(x), 0x114, 0xf, 0xf, true)); // row_shr:4
  x += __int_as_float(__builtin_amdgcn_update_dpp(0, __float_as_int(x), 0x118, 0xf, 0xf, true)); // row_shr:8
  x += __int_as_float(__builtin_amdgcn_update_dpp(0, __float_as_int(x), 0x142, 0xf, 0xf, true)); // row_bcast:15
  x += __int_as_float(__builtin_amdgcn_update_dpp(0, __float_as_int(x), 0x143, 0xf, 0xf, true)); // row_bcast:31
  return x;
}

// ---------------- threefry2x32 (JAX original scheme, key=(0,42)) -------------
__device__ __forceinline__ void threefry2x32_pair(unsigned int x0, unsigned int x1,
                                                  unsigned int* o0, unsigned int* o1) {
  const unsigned int ks0 = 0u, ks1 = 42u, ks2 = 0x1BD11BF0u;
  x0 += ks0; x1 += ks1;
#define TF_R(rot) { x0 += x1; x1 = (x1 << rot) | (x1 >> (32 - rot)); x1 ^= x0; }
  TF_R(13) TF_R(15) TF_R(26) TF_R(6)
  x0 += ks1; x1 += ks2 + 1u;
  TF_R(17) TF_R(29) TF_R(16) TF_R(24)
  x0 += ks2; x1 += ks0 + 2u;
  TF_R(13) TF_R(15) TF_R(26) TF_R(6)
  x0 += ks0; x1 += ks1 + 3u;
  TF_R(17) TF_R(29) TF_R(16) TF_R(24)
  x0 += ks1; x1 += ks2 + 4u;
  TF_R(13) TF_R(15) TF_R(26) TF_R(6)
  x0 += ks2; x1 += ks0 + 5u;
#undef TF_R
  *o0 = x0; *o1 = x1;
}

// bits -> uniform(-1,1) -> sqrt(2)*erfinv. Giles polys TRUNCATED 9->5 terms:
// abs error <= 2.2e-3 (w<5) / 7.5e-3 (w>=5) in the normal sample; noise is
// scaled by ~2e-6, so worst-case output perturbation ~1.4e-7 << 1.05e-5 budget.
__device__ __forceinline__ float fast_normal(unsigned int bits) {
  unsigned int fb = (bits >> 9) | 0x3f800000u;
  float f = __uint_as_float(fb) - 1.0f;                 // [0,1)
  const float lo = -0.99999994039535522461f;            // nextafter(-1,0) f32
  float u = f * 2.0f + lo;
  u = fmaxf(u, lo);
  float w = -__logf(fmaf(-u, u, 1.0f));                 // -log(1-u^2)
  float q1 = w - 2.5f;
  float p1 = 0.00021858087f;
  p1 = fmaf(p1, q1, -0.00125372503f);
  p1 = fmaf(p1, q1, -0.00417768164f);
  p1 = fmaf(p1, q1, 0.246640727f);
  p1 = fmaf(p1, q1, 1.50140941f);
  float q2 = sqrtf(w) - 3.0f;
  float p2 = 0.00573950773f;
  p2 = fmaf(p2, q2, -0.0076224613f);
  p2 = fmaf(p2, q2, 0.00943887047f);
  p2 = fmaf(p2, q2, 1.00167406f);
  p2 = fmaf(p2, q2, 2.83297682f);
  float pr = (w < 5.0f) ? p1 : p2;
  return 1.4142135623730951f * pr * u;
}

// ---------------- K1: ctx MLP + accumulator/barrier zeroing ------------------
__global__ __launch_bounds__(256) void k_ctx(const float* __restrict__ x,
                                             const float* __restrict__ cw,
                                             const float* __restrict__ cb,
                                             float* __restrict__ ws) {
  int gi = blockIdx.x * 256 + threadIdx.x;
  if (gi < REP * NACC) ws[ACC_OFF + gi] = 0.f;
  if (gi == 0) ((unsigned int*)ws)[BAR_IDX] = 0u;

  int lane = threadIdx.x & 63, wv = threadIdx.x >> 6;
  int row = blockIdx.x * 4 + wv;            // 0..839 (grid=210 exactly covers)
  int b = row / OUTF, i = row - b * OUTF;
  const float* wrow = cw + i * CTXD;
  const float* xr = x + b * CTXD;
  float acc = 0.f;
#pragma unroll
  for (int u = 0; u < CTXD; u += 64)
    acc = fmaf(wrow[u + lane], xr[u + lane], acc);
  acc = dpp_sum64(acc);
  if (lane == 63) ws[XT_OFF + row] = acc + cb[i];
}

// ---------------- K2: fused wf + gram + grid barrier + stats + output --------
// Codegen-safe fusion (R3 structure) + the R1-proven occupancy bound.
// CRITICAL: __launch_bounds__(256, 2) is the barrier's deadlock-safety
// guarantee. gfx950 waves can use up to 512 VGPRs (m08); without the bound
// the allocator may exceed 256 VGPRs -> 1 wave/SIMD -> 1 block/CU -> only
// 256/512 blocks resident -> spin barrier deadlocks (R2/R3 hangs). With
// min-2-waves/EU the allocator is REQUIRED to fit VGPR<=256 -> 2 blocks/CU
// -> all 512 blocks co-resident (LDS 7KB is no constraint). R1 ran with
// this exact bound (VGPR=128 there).
// R1 lesson kept: threefry stays OUT of the streaming k-loop (its own flat
// unrolled loop) so wf/nz indexing is compile-time and nothing spills.
__global__ __launch_bounds__(256, 2) void k_fused(const float* __restrict__ wts,
                                                  float* __restrict__ ws,
                                                  float* __restrict__ out) {
  __shared__ float4 mods[32][3];   // [b*8+k][0]=A0,B0  [1]=A1,B1  [2]=biases
  __shared__ float gred[4][NACC];
  __shared__ float G[NACC];                  // [0:144) gram, [144:176) S
  __shared__ float n1[32], Ml[256], vv[32], scl[32], ca[4], wrl[BATCH][9];
  __shared__ float in2[32], mnv[32], sdv[32];

  const float* xt = ws + XT_OFF;
  int t = threadIdx.x;

  if (t < 96) {
    int bk = t / 3, part = t - bk * 3;
    int b = bk >> 3, k = bk & 7;
    const float* xb = xt + b * OUTF + 12 * k;
#define GATE(j) (xb[j] * tanhf(xb[105 + (j)]))
    float4 r;
    if (part < 2) {
      float c0 = GATE(2 * part) + 0.5f;
      float c1 = GATE(2 * part + 1);
      float s0 = GATE(8 + 2 * part) + 1.0f;
      float s1 = GATE(9 + 2 * part);
      float omc = 1.0f - c0;
      r.x = s0 * omc + s1 * c1;   // A_r
      r.y = s1 * omc - s0 * c1;   // A_i
      r.z = s0 * c0 - s1 * c1;    // B_r
      r.w = s1 * c0 + s0 * c1;    // B_i
    } else {
      r.x = GATE(4); r.y = GATE(5); r.z = GATE(6); r.w = GATE(7);
    }
#undef GATE
    mods[bk][part] = r;
  }
  __syncthreads();

  int tp = blockIdx.x * 256 + t;            // 0..131071, 2 adjacent pixels each
  const float4* w4 = (const float4*)wts;    // float4 = 2 complex px; 2^17 per page
  float wf[BATCH][RANK][2];
  // ---- phase A: streaming wf compute (baseline k_wfs body, small & unrollable)
#pragma unroll
  for (int k = 0; k < RANK; ++k) {
    // ld[lerp][comp] = {px0.re, px0.im, px1.re, px1.im}
    float4 ld[2][2];
#pragma unroll
    for (int s = 0; s < 2; ++s)
#pragma unroll
      for (int comp = 0; comp < 2; ++comp)
        ld[s][comp] = w4[((k * 4 + s * 2 + comp) << 17) + tp];
#pragma unroll
    for (int b = 0; b < BATCH; ++b) {
      float4 P  = mods[b * 8 + k][0];
      float4 Q  = mods[b * 8 + k][1];
      float4 Bb = mods[b * 8 + k][2];
#pragma unroll
      for (int j = 0; j < 2; ++j) {
        float w0r = j ? ld[0][0].z : ld[0][0].x;
        float w0i = j ? ld[0][0].w : ld[0][0].y;
        float w1r = j ? ld[1][0].z : ld[1][0].x;
        float w1i = j ? ld[1][0].w : ld[1][0].y;
        float v0r = j ? ld[0][1].z : ld[0][1].x;
        float v0i = j ? ld[0][1].w : ld[0][1].y;
        float v1r = j ? ld[1][1].z : ld[1][1].x;
        float v1i = j ? ld[1][1].w : ld[1][1].y;
        float zr0 = fmaf(P.x, w0r, fmaf(-P.y, w0i, fmaf(P.z, w1r, fmaf(-P.w, w1i, Bb.x))));
        float zi0 = fmaf(P.y, w0r, fmaf( P.x, w0i, fmaf(P.w, w1r, fmaf( P.z, w1i, Bb.y))));
        float zr1 = fmaf(Q.x, v0r, fmaf(-Q.y, v0i, fmaf(Q.z, v1r, fmaf(-Q.w, v1i, Bb.z))));
        float zi1 = fmaf(Q.y, v0r, fmaf( Q.x, v0i, fmaf(Q.w, v1r, fmaf( Q.z, v1i, Bb.w))));
        float d2 = fmaxf(fmaf(zr1, zr1, zi1 * zi1), 1e-12f);
        float rn = __builtin_amdgcn_rsqf(d2);          // v_rsq_f32, ~1 ulp
        wf[b][k][j] = fmaf(zr0, zr1, zi0 * zi1) * rn;  // stays in registers
      }
    }
  }

  // ---- phase B: gram[4][36] + S[4][8] reduction (2-px register pre-sum) ----
  int lane = t & 63, wv = t >> 6;
#pragma unroll
  for (int b = 0; b < BATCH; ++b) {
    int idx = b * 36;
#pragma unroll
    for (int r = 0; r < RANK; ++r)
#pragma unroll
      for (int s2 = r; s2 < RANK; ++s2, ++idx) {
        float pr = dpp_sum64(fmaf(wf[b][r][0], wf[b][s2][0], wf[b][r][1] * wf[b][s2][1]));
        if (lane == 63) gred[wv][idx] = pr;
      }
  }
#pragma unroll
  for (int b = 0; b < BATCH; ++b)
#pragma unroll
    for (int k = 0; k < RANK; ++k) {
      float pr = dpp_sum64(wf[b][k][0] + wf[b][k][1]);
      if (lane == 63) gred[wv][144 + b * 8 + k] = pr;
    }
  __syncthreads();
  for (int i = t; i < NACC; i += 256) {
    float s = gred[0][i] + gred[1][i] + gred[2][i] + gred[3][i];
    // 8-way replicated accumulators: same-address contention /8
    atomicAdd(ws + ACC_OFF + (blockIdx.x & (REP - 1)) * NACC + i, s);
  }

  // ---- phase C: noise threefry (separate flat loop, small bodies) ----------
  // Placed between the atomic publish and the barrier: pure VALU that fills
  // the block-arrival skew. nz indices are compile-time after unroll.
  __half2 nzA[16], nzB[16];                 // 64 normals, fp16-packed in regs
#pragma unroll
  for (int bk = 0; bk < 16; ++bk) {
    unsigned int i0 = ((unsigned int)bk << 18) + 2u * (unsigned int)tp;
    unsigned int ra0, ra1, rb0, rb1;
    threefry2x32_pair(i0,      i0 + 0x400000u, &ra0, &ra1);
    threefry2x32_pair(i0 + 1u, i0 + 0x400001u, &rb0, &rb1);
    nzA[bk] = __halves2half2(__float2half(fast_normal(ra0)), __float2half(fast_normal(rb0)));
    nzB[bk] = __halves2half2(__float2half(fast_normal(ra1)), __float2half(fast_normal(rb1)));
  }

  // ---- device-scope grid barrier (512 blocks co-resident by launch bound) --
  __syncthreads();
  if (t == 0) {
    unsigned int* bar = (unsigned int*)ws + BAR_IDX;
    __hip_atomic_fetch_add(bar, 1u, __ATOMIC_ACQ_REL, __HIP_MEMORY_SCOPE_AGENT);
    while (__hip_atomic_load(bar, __ATOMIC_ACQUIRE, __HIP_MEMORY_SCOPE_AGENT) < (unsigned int)NBLK)
      __builtin_amdgcn_s_sleep(1);
  }
  __syncthreads();

  // ---- phase D: analytic stats (redundant per block; trivial ALU) ----------
  if (t < NACC) {
    float s = 0.f;
#pragma unroll
    for (int rep = 0; rep < REP; ++rep)
      s += __hip_atomic_load(ws + ACC_OFF + rep * NACC + t,
                             __ATOMIC_RELAXED, __HIP_MEMORY_SCOPE_AGENT);
    G[t] = s;
  }
  if (t >= 192 && t < 192 + BATCH) {         // wr softmax (per-batch thread)
    int b = t - 192;
    float raw[9];
#pragma unroll
    for (int j = 0; j < 9; ++j)
      raw[j] = xt[b * OUTF + 96 + j] * tanhf(xt[b * OUTF + 201 + j]);
    raw[8] += 0.35355339059327373f;          // 1/sqrt(8)
    double ss = 0.0;
#pragma unroll
    for (int j = 0; j < 9; ++j) ss += (double)raw[j] * (double)raw[j];
    float n = fmaxf((float)sqrt(ss), 1e-12f);
    float y[9]; float m = -1e30f;
#pragma unroll
    for (int j = 0; j < 9; ++j) { y[j] = raw[j] / n; m = fmaxf(m, y[j]); }
    float e[9]; double se = 0.0;
#pragma unroll
    for (int j = 0; j < 9; ++j) { e[j] = expf(y[j] - m); se += (double)e[j]; }
#pragma unroll
    for (int j = 0; j < 9; ++j) wrl[b][j] = e[j] / (float)se;
  }
  __syncthreads();
  if (t < 32) {
    int b = t >> 3, k = t & 7;
    int di = k * 8 - (k * (k - 1)) / 2;
    n1[t] = fmaxf(sqrtf(G[b * 36 + di]), 1e-12f);
  }
  __syncthreads();
  {
    int b = t >> 6, k = (t >> 3) & 7, s = t & 7;
    float m;
    if (k == s) {
      m = 1.0f / n1[b * 8 + k];
    } else {
      int r0 = k < s ? k : s, s0 = k < s ? s : k;
      int gi = r0 * 8 - (r0 * (r0 - 1)) / 2 + (s0 - r0);
      float simv = G[b * 36 + gi] / (n1[b * 8 + k] * n1[b * 8 + s]);
      m = -0.0050507627227610544f * simv / n1[b * 8 + s];  // (0.1/sqrt(8))/7
    }
    Ml[t] = m;
  }
  __syncthreads();
  if (t < 32) {
    int b = t >> 3, k = t & 7;
    // sum = M.S ; sumsq = (M G M^T)_kk — exact linear algebra of the 2nd pass
    float sum = 0.f, sq = 0.f;
#pragma unroll
    for (int s = 0; s < 8; ++s) {
      float ms = Ml[b * 64 + k * 8 + s];
      sum = fmaf(ms, G[144 + b * 8 + s], sum);
#pragma unroll
      for (int u = 0; u < 8; ++u) {
        int r0 = s < u ? s : u, s0 = s < u ? u : s;
        int gi = r0 * 8 - (r0 * (r0 - 1)) / 2 + (s0 - r0);
        sq = fmaf(ms * Ml[b * 64 + k * 8 + u], G[b * 36 + gi], sq);
      }
    }
    float n2 = fmaxf(sqrtf(fmaxf(sq, 0.f)), 1e-12f);
    float mean = sum / n2 * (1.0f / NPIX);
    float sy2 = sq / (n2 * n2);
    float var = (sy2 - (float)NPIX * mean * mean) * (1.0f / (float)(NPIX - 1));
    var = fmaxf(var, 0.f);
    float sd = fmaxf(sqrtf(var), 1e-12f);
    in2[t] = 1.f / n2; mnv[t] = mean; sdv[t] = sd;
  }
  __syncthreads();
  if (t < 32) {
    int b = t >> 3, s = t & 7;
    float acc = 0.f;
#pragma unroll
    for (int k = 0; k < 8; ++k)
      acc += wrl[b][k] * Ml[b * 64 + k * 8 + s] * in2[b * 8 + k];
    vv[t] = acc;
    scl[t] = wrl[b][s] * 0.01f * sdv[t];
  }
  if (t < BATCH) {
    float a = 0.f;
#pragma unroll
    for (int k = 0; k < 8; ++k) a += wrl[t][k] * 0.01f * mnv[t * 8 + k];
    ca[t] = a;
  }
  __syncthreads();

  // ---- phase E: output from fp32 wf regs + register-held noise -------------
  float o0[4], o1[4];
#pragma unroll
  for (int b = 0; b < 4; ++b) { o0[b] = ca[b]; o1[b] = ca[b]; }
#pragma unroll
  for (int b = 0; b < 4; ++b)
#pragma unroll
    for (int s = 0; s < 8; ++s) {
      float v = vv[b * 8 + s];
      o0[b] = fmaf(v, wf[b][s][0], o0[b]);
      o1[b] = fmaf(v, wf[b][s][1], o1[b]);
    }
#pragma unroll
  for (int b2 = 0; b2 < 2; ++b2)
#pragma unroll
    for (int k = 0; k < 8; ++k) {
      int bk = b2 * 8 + k;
      o0[b2]     = fmaf(scl[b2 * 8 + k],       __low2float (nzA[bk]), o0[b2]);
      o1[b2]     = fmaf(scl[b2 * 8 + k],       __high2float(nzA[bk]), o1[b2]);
      o0[b2 + 2] = fmaf(scl[(b2 + 2) * 8 + k], __low2float (nzB[bk]), o0[b2 + 2]);
      o1[b2 + 2] = fmaf(scl[(b2 + 2) * 8 + k], __high2float(nzB[bk]), o1[b2 + 2]);
    }
#pragma unroll
  for (int b = 0; b < 4; ++b)
    ((float2*)out)[(b << 17) + tp] = make_float2(o0[b], o1[b]);  // coalesced 8B
}

extern "C" void kernel_launch(void* const* d_in, const int* in_sizes, int n_in,
                              void* d_out, int out_size, void* d_ws, size_t ws_size,
                              hipStream_t stream) {
  const float* x   = (const float*)d_in[0];
  const float* cw  = (const float*)d_in[1];
  const float* cb  = (const float*)d_in[2];
  const float* wts = (const float*)d_in[3];
  float* out = (float*)d_out;
  float* ws  = (float*)d_ws;

  k_ctx  <<<210,  256, 0, stream>>>(x, cw, cb, ws);   // xt + zero ACC/barrier
  k_fused<<<NBLK, 256, 0, stream>>>(wts, ws, out);    // everything else
}

// Round 5
// 287.231 us; speedup vs baseline: 1.0483x; 1.0290x over previous
//
#include <hip/hip_runtime.h>
#include <hip/hip_fp16.h>
#include <math.h>

#define NPIX 262144   // 512*512
#define BATCH 4
#define RANK 8
#define CTXD 512
#define OUTF 210

// ---- workspace layout (float offsets) ----
#define XT_OFF   0      // xt[4][210] (840 floats)
#define BAR_IDX  1016   // uint spin-barrier counter (zeroed by k_ctx)
#define ACC_OFF  1024   // 8 replicas x 176 accumulators (gram[4][36], S[4][8])
#define REP      8
#define NACC     176
#define NBLK     512    // fused-kernel grid

// ---------------- wave64 sum via DPP (result in lane 63) ---------------------
__device__ __forceinline__ float dpp_sum64(float x) {
  x += __int_as_float(__builtin_amdgcn_update_dpp(0, __float_as_int(x), 0x111, 0xf, 0xf, true)); // row_shr:1
  x += __int_as_float(__builtin_amdgcn_update_dpp(0, __float_as_int(x), 0x112, 0xf, 0xf, true)); // row_shr:2
  x += __int_as_float(__builtin_amdgcn_update_dpp(0, __float_as_int(x), 0x114, 0xf, 0xf, true)); // row_shr:4
  x += __int_as_float(__builtin_amdgcn_update_dpp(0, __float_as_int(x), 0x118, 0xf, 0xf, true)); // row_shr:8
  x += __int_as_float(__builtin_amdgcn_update_dpp(0, __float_as_int(x), 0x142, 0xf, 0xf, true)); // row_bcast:15
  x += __int_as_float(__builtin_amdgcn_update_dpp(0, __float_as_int(x), 0x143, 0xf, 0xf, true)); // row_bcast:31
  return x;
}

// ---------------- threefry2x32 (JAX original scheme, key=(0,42)) -------------
__device__ __forceinline__ void threefry2x32_pair(unsigned int x0, unsigned int x1,
                                                  unsigned int* o0, unsigned int* o1) {
  const unsigned int ks0 = 0u, ks1 = 42u, ks2 = 0x1BD11BF0u;
  x0 += ks0; x1 += ks1;
#define TF_R(rot) { x0 += x1; x1 = (x1 << rot) | (x1 >> (32 - rot)); x1 ^= x0; }
  TF_R(13) TF_R(15) TF_R(26) TF_R(6)
  x0 += ks1; x1 += ks2 + 1u;
  TF_R(17) TF_R(29) TF_R(16) TF_R(24)
  x0 += ks2; x1 += ks0 + 2u;
  TF_R(13) TF_R(15) TF_R(26) TF_R(6)
  x0 += ks0; x1 += ks1 + 3u;
  TF_R(17) TF_R(29) TF_R(16) TF_R(24)
  x0 += ks1; x1 += ks2 + 4u;
  TF_R(13) TF_R(15) TF_R(26) TF_R(6)
  x0 += ks2; x1 += ks0 + 5u;
#undef TF_R
  *o0 = x0; *o1 = x1;
}

// bits -> uniform(-1,1) -> sqrt(2)*erfinv. Giles polys TRUNCATED 9->5 terms:
// abs error <= 2.2e-3 (w<5) / 7.5e-3 (w>=5) in the normal sample; noise is
// scaled by ~2e-6, so worst-case output perturbation ~1.4e-7 << 1.05e-5 budget.
__device__ __forceinline__ float fast_normal(unsigned int bits) {
  unsigned int fb = (bits >> 9) | 0x3f800000u;
  float f = __uint_as_float(fb) - 1.0f;                 // [0,1)
  const float lo = -0.99999994039535522461f;            // nextafter(-1,0) f32
  float u = f * 2.0f + lo;
  u = fmaxf(u, lo);
  float w = -__logf(fmaf(-u, u, 1.0f));                 // -log(1-u^2)
  float q1 = w - 2.5f;
  float p1 = 0.00021858087f;
  p1 = fmaf(p1, q1, -0.00125372503f);
  p1 = fmaf(p1, q1, -0.00417768164f);
  p1 = fmaf(p1, q1, 0.246640727f);
  p1 = fmaf(p1, q1, 1.50140941f);
  float q2 = sqrtf(w) - 3.0f;
  float p2 = 0.00573950773f;
  p2 = fmaf(p2, q2, -0.0076224613f);
  p2 = fmaf(p2, q2, 0.00943887047f);
  p2 = fmaf(p2, q2, 1.00167406f);
  p2 = fmaf(p2, q2, 2.83297682f);
  float pr = (w < 5.0f) ? p1 : p2;
  return 1.4142135623730951f * pr * u;
}

// ---------------- K1: ctx MLP + accumulator/barrier zeroing ------------------
__global__ __launch_bounds__(256) void k_ctx(const float* __restrict__ x,
                                             const float* __restrict__ cw,
                                             const float* __restrict__ cb,
                                             float* __restrict__ ws) {
  int gi = blockIdx.x * 256 + threadIdx.x;
  if (gi < REP * NACC) ws[ACC_OFF + gi] = 0.f;
  if (gi == 0) ((unsigned int*)ws)[BAR_IDX] = 0u;

  int lane = threadIdx.x & 63, wv = threadIdx.x >> 6;
  int row = blockIdx.x * 4 + wv;            // 0..839 (grid=210 exactly covers)
  int b = row / OUTF, i = row - b * OUTF;
  const float* wrow = cw + i * CTXD;
  const float* xr = x + b * CTXD;
  float acc = 0.f;
#pragma unroll
  for (int u = 0; u < CTXD; u += 64)
    acc = fmaf(wrow[u + lane], xr[u + lane], acc);
  acc = dpp_sum64(acc);
  if (lane == 63) ws[XT_OFF + row] = acc + cb[i];
}

// ---------------- K2: fused wf + gram + grid barrier + stats + output --------
// R4 post-mortem: VGPR_Count=128 + 145 MB scratch writes in BOTH R1 and R4
// (identical counters) => the allocator, given only a MIN of 2 waves/EU,
// chose to target 4 waves/EU (VGPR cap 128, the m69 occupancy step) and
// spilled the ~180-200 dwords of live state. NOT an unroll/SROA problem —
// phase A/B is the baseline k_wfs body that never spilled under 128 live.
// FIX: amdgpu_waves_per_eu(2,2) clamps min AND max to 2 waves/EU => register
// budget exactly 256 VGPRs => live state fits, zero scratch. Occupancy
// becomes exactly 2 blocks/CU => all 512 blocks co-resident => the spin
// barrier remains deadlock-free by construction.
__global__ __attribute__((amdgpu_waves_per_eu(2, 2))) __launch_bounds__(256)
void k_fused(const float* __restrict__ wts,
             float* __restrict__ ws,
             float* __restrict__ out) {
  __shared__ float4 mods[32][3];   // [b*8+k][0]=A0,B0  [1]=A1,B1  [2]=biases
  __shared__ float gred[4][NACC];
  __shared__ float G[NACC];                  // [0:144) gram, [144:176) S
  __shared__ float n1[32], Ml[256], vv[32], scl[32], ca[4], wrl[BATCH][9];
  __shared__ float in2[32], mnv[32], sdv[32];

  const float* xt = ws + XT_OFF;
  int t = threadIdx.x;

  if (t < 96) {
    int bk = t / 3, part = t - bk * 3;
    int b = bk >> 3, k = bk & 7;
    const float* xb = xt + b * OUTF + 12 * k;
#define GATE(j) (xb[j] * tanhf(xb[105 + (j)]))
    float4 r;
    if (part < 2) {
      float c0 = GATE(2 * part) + 0.5f;
      float c1 = GATE(2 * part + 1);
      float s0 = GATE(8 + 2 * part) + 1.0f;
      float s1 = GATE(9 + 2 * part);
      float omc = 1.0f - c0;
      r.x = s0 * omc + s1 * c1;   // A_r
      r.y = s1 * omc - s0 * c1;   // A_i
      r.z = s0 * c0 - s1 * c1;    // B_r
      r.w = s1 * c0 + s0 * c1;    // B_i
    } else {
      r.x = GATE(4); r.y = GATE(5); r.z = GATE(6); r.w = GATE(7);
    }
#undef GATE
    mods[bk][part] = r;
  }
  __syncthreads();

  int tp = blockIdx.x * 256 + t;            // 0..131071, 2 adjacent pixels each
  const float4* w4 = (const float4*)wts;    // float4 = 2 complex px; 2^17 per page
  float wf[BATCH][RANK][2];
  // ---- phase A: streaming wf compute (baseline k_wfs body, small & unrollable)
#pragma unroll
  for (int k = 0; k < RANK; ++k) {
    // ld[lerp][comp] = {px0.re, px0.im, px1.re, px1.im}
    float4 ld[2][2];
#pragma unroll
    for (int s = 0; s < 2; ++s)
#pragma unroll
      for (int comp = 0; comp < 2; ++comp)
        ld[s][comp] = w4[((k * 4 + s * 2 + comp) << 17) + tp];
#pragma unroll
    for (int b = 0; b < BATCH; ++b) {
      float4 P  = mods[b * 8 + k][0];
      float4 Q  = mods[b * 8 + k][1];
      float4 Bb = mods[b * 8 + k][2];
#pragma unroll
      for (int j = 0; j < 2; ++j) {
        float w0r = j ? ld[0][0].z : ld[0][0].x;
        float w0i = j ? ld[0][0].w : ld[0][0].y;
        float w1r = j ? ld[1][0].z : ld[1][0].x;
        float w1i = j ? ld[1][0].w : ld[1][0].y;
        float v0r = j ? ld[0][1].z : ld[0][1].x;
        float v0i = j ? ld[0][1].w : ld[0][1].y;
        float v1r = j ? ld[1][1].z : ld[1][1].x;
        float v1i = j ? ld[1][1].w : ld[1][1].y;
        float zr0 = fmaf(P.x, w0r, fmaf(-P.y, w0i, fmaf(P.z, w1r, fmaf(-P.w, w1i, Bb.x))));
        float zi0 = fmaf(P.y, w0r, fmaf( P.x, w0i, fmaf(P.w, w1r, fmaf( P.z, w1i, Bb.y))));
        float zr1 = fmaf(Q.x, v0r, fmaf(-Q.y, v0i, fmaf(Q.z, v1r, fmaf(-Q.w, v1i, Bb.z))));
        float zi1 = fmaf(Q.y, v0r, fmaf( Q.x, v0i, fmaf(Q.w, v1r, fmaf( Q.z, v1i, Bb.w))));
        float d2 = fmaxf(fmaf(zr1, zr1, zi1 * zi1), 1e-12f);
        float rn = __builtin_amdgcn_rsqf(d2);          // v_rsq_f32, ~1 ulp
        wf[b][k][j] = fmaf(zr0, zr1, zi0 * zi1) * rn;  // stays in registers
      }
    }
  }

  // ---- phase B: gram[4][36] + S[4][8] reduction (2-px register pre-sum) ----
  int lane = t & 63, wv = t >> 6;
#pragma unroll
  for (int b = 0; b < BATCH; ++b) {
    int idx = b * 36;
#pragma unroll
    for (int r = 0; r < RANK; ++r)
#pragma unroll
      for (int s2 = r; s2 < RANK; ++s2, ++idx) {
        float pr = dpp_sum64(fmaf(wf[b][r][0], wf[b][s2][0], wf[b][r][1] * wf[b][s2][1]));
        if (lane == 63) gred[wv][idx] = pr;
      }
  }
#pragma unroll
  for (int b = 0; b < BATCH; ++b)
#pragma unroll
    for (int k = 0; k < RANK; ++k) {
      float pr = dpp_sum64(wf[b][k][0] + wf[b][k][1]);
      if (lane == 63) gred[wv][144 + b * 8 + k] = pr;
    }
  __syncthreads();
  for (int i = t; i < NACC; i += 256) {
    float s = gred[0][i] + gred[1][i] + gred[2][i] + gred[3][i];
    // 8-way replicated accumulators: same-address contention /8
    atomicAdd(ws + ACC_OFF + (blockIdx.x & (REP - 1)) * NACC + i, s);
  }

  // ---- phase C: noise threefry (separate flat loop, small bodies) ----------
  // Placed between the atomic publish and the barrier: pure VALU that fills
  // the block-arrival skew. nz indices are compile-time after unroll.
  __half2 nzA[16], nzB[16];                 // 64 normals, fp16-packed in regs
#pragma unroll
  for (int bk = 0; bk < 16; ++bk) {
    unsigned int i0 = ((unsigned int)bk << 18) + 2u * (unsigned int)tp;
    unsigned int ra0, ra1, rb0, rb1;
    threefry2x32_pair(i0,      i0 + 0x400000u, &ra0, &ra1);
    threefry2x32_pair(i0 + 1u, i0 + 0x400001u, &rb0, &rb1);
    nzA[bk] = __halves2half2(__float2half(fast_normal(ra0)), __float2half(fast_normal(rb0)));
    nzB[bk] = __halves2half2(__float2half(fast_normal(ra1)), __float2half(fast_normal(rb1)));
  }

  // ---- device-scope grid barrier (512 blocks co-resident by waves_per_eu) --
  __syncthreads();
  if (t == 0) {
    unsigned int* bar = (unsigned int*)ws + BAR_IDX;
    __hip_atomic_fetch_add(bar, 1u, __ATOMIC_ACQ_REL, __HIP_MEMORY_SCOPE_AGENT);
    while (__hip_atomic_load(bar, __ATOMIC_ACQUIRE, __HIP_MEMORY_SCOPE_AGENT) < (unsigned int)NBLK)
      __builtin_amdgcn_s_sleep(1);
  }
  __syncthreads();

  // ---- phase D: analytic stats (redundant per block; trivial ALU) ----------
  if (t < NACC) {
    float s = 0.f;
#pragma unroll
    for (int rep = 0; rep < REP; ++rep)
      s += __hip_atomic_load(ws + ACC_OFF + rep * NACC + t,
                             __ATOMIC_RELAXED, __HIP_MEMORY_SCOPE_AGENT);
    G[t] = s;
  }
  if (t >= 192 && t < 192 + BATCH) {         // wr softmax (per-batch thread)
    int b = t - 192;
    float raw[9];
#pragma unroll
    for (int j = 0; j < 9; ++j)
      raw[j] = xt[b * OUTF + 96 + j] * tanhf(xt[b * OUTF + 201 + j]);
    raw[8] += 0.35355339059327373f;          // 1/sqrt(8)
    double ss = 0.0;
#pragma unroll
    for (int j = 0; j < 9; ++j) ss += (double)raw[j] * (double)raw[j];
    float n = fmaxf((float)sqrt(ss), 1e-12f);
    float y[9]; float m = -1e30f;
#pragma unroll
    for (int j = 0; j < 9; ++j) { y[j] = raw[j] / n; m = fmaxf(m, y[j]); }
    float e[9]; double se = 0.0;
#pragma unroll
    for (int j = 0; j < 9; ++j) { e[j] = expf(y[j] - m); se += (double)e[j]; }
#pragma unroll
    for (int j = 0; j < 9; ++j) wrl[b][j] = e[j] / (float)se;
  }
  __syncthreads();
  if (t < 32) {
    int b = t >> 3, k = t & 7;
    int di = k * 8 - (k * (k - 1)) / 2;
    n1[t] = fmaxf(sqrtf(G[b * 36 + di]), 1e-12f);
  }
  __syncthreads();
  {
    int b = t >> 6, k = (t >> 3) & 7, s = t & 7;
    float m;
    if (k == s) {
      m = 1.0f / n1[b * 8 + k];
    } else {
      int r0 = k < s ? k : s, s0 = k < s ? s : k;
      int gi = r0 * 8 - (r0 * (r0 - 1)) / 2 + (s0 - r0);
      float simv = G[b * 36 + gi] / (n1[b * 8 + k] * n1[b * 8 + s]);
      m = -0.0050507627227610544f * simv / n1[b * 8 + s];  // (0.1/sqrt(8))/7
    }
    Ml[t] = m;
  }
  __syncthreads();
  if (t < 32) {
    int b = t >> 3, k = t & 7;
    // sum = M.S ; sumsq = (M G M^T)_kk — exact linear algebra of the 2nd pass
    float sum = 0.f, sq = 0.f;
#pragma unroll
    for (int s = 0; s < 8; ++s) {
      float ms = Ml[b * 64 + k * 8 + s];
      sum = fmaf(ms, G[144 + b * 8 + s], sum);
#pragma unroll
      for (int u = 0; u < 8; ++u) {
        int r0 = s < u ? s : u, s0 = s < u ? u : s;
        int gi = r0 * 8 - (r0 * (r0 - 1)) / 2 + (s0 - r0);
        sq = fmaf(ms * Ml[b * 64 + k * 8 + u], G[b * 36 + gi], sq);
      }
    }
    float n2 = fmaxf(sqrtf(fmaxf(sq, 0.f)), 1e-12f);
    float mean = sum / n2 * (1.0f / NPIX);
    float sy2 = sq / (n2 * n2);
    float var = (sy2 - (float)NPIX * mean * mean) * (1.0f / (float)(NPIX - 1));
    var = fmaxf(var, 0.f);
    float sd = fmaxf(sqrtf(var), 1e-12f);
    in2[t] = 1.f / n2; mnv[t] = mean; sdv[t] = sd;
  }
  __syncthreads();
  if (t < 32) {
    int b = t >> 3, s = t & 7;
    float acc = 0.f;
#pragma unroll
    for (int k = 0; k < 8; ++k)
      acc += wrl[b][k] * Ml[b * 64 + k * 8 + s] * in2[b * 8 + k];
    vv[t] = acc;
    scl[t] = wrl[b][s] * 0.01f * sdv[t];
  }
  if (t < BATCH) {
    float a = 0.f;
#pragma unroll
    for (int k = 0; k < 8; ++k) a += wrl[t][k] * 0.01f * mnv[t * 8 + k];
    ca[t] = a;
  }
  __syncthreads();

  // ---- phase E: output from fp32 wf regs + register-held noise -------------
  float o0[4], o1[4];
#pragma unroll
  for (int b = 0; b < 4; ++b) { o0[b] = ca[b]; o1[b] = ca[b]; }
#pragma unroll
  for (int b = 0; b < 4; ++b)
#pragma unroll
    for (int s = 0; s < 8; ++s) {
      float v = vv[b * 8 + s];
      o0[b] = fmaf(v, wf[b][s][0], o0[b]);
      o1[b] = fmaf(v, wf[b][s][1], o1[b]);
    }
#pragma unroll
  for (int b2 = 0; b2 < 2; ++b2)
#pragma unroll
    for (int k = 0; k < 8; ++k) {
      int bk = b2 * 8 + k;
      o0[b2]     = fmaf(scl[b2 * 8 + k],       __low2float (nzA[bk]), o0[b2]);
      o1[b2]     = fmaf(scl[b2 * 8 + k],       __high2float(nzA[bk]), o1[b2]);
      o0[b2 + 2] = fmaf(scl[(b2 + 2) * 8 + k], __low2float (nzB[bk]), o0[b2 + 2]);
      o1[b2 + 2] = fmaf(scl[(b2 + 2) * 8 + k], __high2float(nzB[bk]), o1[b2 + 2]);
    }
#pragma unroll
  for (int b = 0; b < 4; ++b)
    ((float2*)out)[(b << 17) + tp] = make_float2(o0[b], o1[b]);  // coalesced 8B
}

extern "C" void kernel_launch(void* const* d_in, const int* in_sizes, int n_in,
                              void* d_out, int out_size, void* d_ws, size_t ws_size,
                              hipStream_t stream) {
  const float* x   = (const float*)d_in[0];
  const float* cw  = (const float*)d_in[1];
  const float* cb  = (const float*)d_in[2];
  const float* wts = (const float*)d_in[3];
  float* out = (float*)d_out;
  float* ws  = (float*)d_ws;

  k_ctx  <<<210,  256, 0, stream>>>(x, cw, cb, ws);   // xt + zero ACC/barrier
  k_fused<<<NBLK, 256, 0, stream>>>(wts, ws, out);    // everything else
}

// Round 6
// 261.241 us; speedup vs baseline: 1.1526x; 1.0995x over previous
//
#include <hip/hip_runtime.h>
#include <hip/hip_fp16.h>
#include <math.h>

#define NPIX 262144   // 512*512
#define BATCH 4
#define RANK 8
#define CTXD 512
#define OUTF 210

// ---- workspace layout (float offsets) ----
#define XT_OFF   0      // xt[4][210] (840 floats)
#define BAR_IDX  1016   // uint spin-barrier counter (zeroed by k_ctx)
#define ACC_OFF  1024   // 8 replicas x 176 accumulators (gram[4][36], S[4][8])
#define REP      8
#define NACC     176
#define NBLK     512    // fused-kernel grid
#define WFL_BYTES 65536 // dynamic LDS: wfl[64][256] f32

// ---------------- wave64 sum via DPP (result in lane 63) ---------------------
__device__ __forceinline__ float dpp_sum64(float x) {
  x += __int_as_float(__builtin_amdgcn_update_dpp(0, __float_as_int(x), 0x111, 0xf, 0xf, true)); // row_shr:1
  x += __int_as_float(__builtin_amdgcn_update_dpp(0, __float_as_int(x), 0x112, 0xf, 0xf, true)); // row_shr:2
  x += __int_as_float(__builtin_amdgcn_update_dpp(0, __float_as_int(x), 0x114, 0xf, 0xf, true)); // row_shr:4
  x += __int_as_float(__builtin_amdgcn_update_dpp(0, __float_as_int(x), 0x118, 0xf, 0xf, true)); // row_shr:8
  x += __int_as_float(__builtin_amdgcn_update_dpp(0, __float_as_int(x), 0x142, 0xf, 0xf, true)); // row_bcast:15
  x += __int_as_float(__builtin_amdgcn_update_dpp(0, __float_as_int(x), 0x143, 0xf, 0xf, true)); // row_bcast:31
  return x;
}

// ---------------- threefry2x32 (JAX original scheme, key=(0,42)) -------------
__device__ __forceinline__ void threefry2x32_pair(unsigned int x0, unsigned int x1,
                                                  unsigned int* o0, unsigned int* o1) {
  const unsigned int ks0 = 0u, ks1 = 42u, ks2 = 0x1BD11BF0u;
  x0 += ks0; x1 += ks1;
#define TF_R(rot) { x0 += x1; x1 = (x1 << rot) | (x1 >> (32 - rot)); x1 ^= x0; }
  TF_R(13) TF_R(15) TF_R(26) TF_R(6)
  x0 += ks1; x1 += ks2 + 1u;
  TF_R(17) TF_R(29) TF_R(16) TF_R(24)
  x0 += ks2; x1 += ks0 + 2u;
  TF_R(13) TF_R(15) TF_R(26) TF_R(6)
  x0 += ks0; x1 += ks1 + 3u;
  TF_R(17) TF_R(29) TF_R(16) TF_R(24)
  x0 += ks1; x1 += ks2 + 4u;
  TF_R(13) TF_R(15) TF_R(26) TF_R(6)
  x0 += ks2; x1 += ks0 + 5u;
#undef TF_R
  *o0 = x0; *o1 = x1;
}

// bits -> uniform(-1,1) -> sqrt(2)*erfinv. Giles polys TRUNCATED 9->5 terms:
// abs error <= 2.2e-3 (w<5) / 7.5e-3 (w>=5) in the normal sample; noise is
// scaled by ~2e-6, so worst-case output perturbation ~1.4e-7 << 1.05e-5 budget.
__device__ __forceinline__ float fast_normal(unsigned int bits) {
  unsigned int fb = (bits >> 9) | 0x3f800000u;
  float f = __uint_as_float(fb) - 1.0f;                 // [0,1)
  const float lo = -0.99999994039535522461f;            // nextafter(-1,0) f32
  float u = f * 2.0f + lo;
  u = fmaxf(u, lo);
  float w = -__logf(fmaf(-u, u, 1.0f));                 // -log(1-u^2)
  float q1 = w - 2.5f;
  float p1 = 0.00021858087f;
  p1 = fmaf(p1, q1, -0.00125372503f);
  p1 = fmaf(p1, q1, -0.00417768164f);
  p1 = fmaf(p1, q1, 0.246640727f);
  p1 = fmaf(p1, q1, 1.50140941f);
  float q2 = sqrtf(w) - 3.0f;
  float p2 = 0.00573950773f;
  p2 = fmaf(p2, q2, -0.0076224613f);
  p2 = fmaf(p2, q2, 0.00943887047f);
  p2 = fmaf(p2, q2, 1.00167406f);
  p2 = fmaf(p2, q2, 2.83297682f);
  float pr = (w < 5.0f) ? p1 : p2;
  return 1.4142135623730951f * pr * u;
}

// ---------------- K1: ctx MLP + accumulator/barrier zeroing ------------------
__global__ __launch_bounds__(256) void k_ctx(const float* __restrict__ x,
                                             const float* __restrict__ cw,
                                             const float* __restrict__ cb,
                                             float* __restrict__ ws) {
  int gi = blockIdx.x * 256 + threadIdx.x;
  if (gi < REP * NACC) ws[ACC_OFF + gi] = 0.f;
  if (gi == 0) ((unsigned int*)ws)[BAR_IDX] = 0u;

  int lane = threadIdx.x & 63, wv = threadIdx.x >> 6;
  int row = blockIdx.x * 4 + wv;            // 0..839 (grid=210 exactly covers)
  int b = row / OUTF, i = row - b * OUTF;
  const float* wrow = cw + i * CTXD;
  const float* xr = x + b * CTXD;
  float acc = 0.f;
#pragma unroll
  for (int u = 0; u < CTXD; u += 64)
    acc = fmaf(wrow[u + lane], xr[u + lane], acc);
  acc = dpp_sum64(acc);
  if (lane == 63) ws[XT_OFF + row] = acc + cb[i];
}

// ---------------- K2: fused wf + gram + grid barrier + stats + output --------
// R5 post-mortem: raising the register BUDGET failed twice (launch_bounds(,2)
// and waves_per_eu(2,2) both -> VGPR=128 + ~1.1KB/thread scratch, 216us).
// This version LOWERS THE PRESSURE instead:
//  * wf[4][8][2] is staged to LDS (wfl[64][256] f32, 64KB dynamic) across the
//    grid barrier — across-barrier register state ~0. Layout [value][thread]:
//    lane-consecutive 4B columns, conflict-free on write and read.
//  * noise threefry moves AFTER the barrier, folded directly into the output
//    accumulators — the 32-reg nzA/nzB arrays are gone.
//  * 71KB total LDS pins occupancy to exactly 2 blocks/CU: the backend's own
//    occupancy calc then sets the VGPR budget to 256 (huge slack), and the
//    barrier's co-residency (512 blocks on 256 CUs) is enforced by LDS
//    geometry alone. __launch_bounds__(256,2) keeps the VGPR<=256 guarantee.
__global__ __launch_bounds__(256, 2) void k_fused(const float* __restrict__ wts,
                                                  float* __restrict__ ws,
                                                  float* __restrict__ out) {
  extern __shared__ float wfl[];             // [64][256] value-major wf store
  __shared__ float4 mods[32][3];   // [b*8+k][0]=A0,B0  [1]=A1,B1  [2]=biases
  __shared__ float gred[4][NACC];
  __shared__ float G[NACC];                  // [0:144) gram, [144:176) S
  __shared__ float n1[32], Ml[256], vv[32], scl[32], ca[4], wrl[BATCH][9];
  __shared__ float in2[32], mnv[32], sdv[32];

  const float* xt = ws + XT_OFF;
  int t = threadIdx.x;

  if (t < 96) {
    int bk = t / 3, part = t - bk * 3;
    int b = bk >> 3, k = bk & 7;
    const float* xb = xt + b * OUTF + 12 * k;
#define GATE(j) (xb[j] * tanhf(xb[105 + (j)]))
    float4 r;
    if (part < 2) {
      float c0 = GATE(2 * part) + 0.5f;
      float c1 = GATE(2 * part + 1);
      float s0 = GATE(8 + 2 * part) + 1.0f;
      float s1 = GATE(9 + 2 * part);
      float omc = 1.0f - c0;
      r.x = s0 * omc + s1 * c1;   // A_r
      r.y = s1 * omc - s0 * c1;   // A_i
      r.z = s0 * c0 - s1 * c1;    // B_r
      r.w = s1 * c0 + s0 * c1;    // B_i
    } else {
      r.x = GATE(4); r.y = GATE(5); r.z = GATE(6); r.w = GATE(7);
    }
#undef GATE
    mods[bk][part] = r;
  }
  __syncthreads();

  int tp = blockIdx.x * 256 + t;            // 0..131071, 2 adjacent pixels each
  const float4* w4 = (const float4*)wts;    // float4 = 2 complex px; 2^17 per page
  float wf[BATCH][RANK][2];
  // ---- phase A: streaming wf compute (baseline k_wfs body, small & unrollable)
#pragma unroll
  for (int k = 0; k < RANK; ++k) {
    // ld[lerp][comp] = {px0.re, px0.im, px1.re, px1.im}
    float4 ld[2][2];
#pragma unroll
    for (int s = 0; s < 2; ++s)
#pragma unroll
      for (int comp = 0; comp < 2; ++comp)
        ld[s][comp] = w4[((k * 4 + s * 2 + comp) << 17) + tp];
#pragma unroll
    for (int b = 0; b < BATCH; ++b) {
      float4 P  = mods[b * 8 + k][0];
      float4 Q  = mods[b * 8 + k][1];
      float4 Bb = mods[b * 8 + k][2];
#pragma unroll
      for (int j = 0; j < 2; ++j) {
        float w0r = j ? ld[0][0].z : ld[0][0].x;
        float w0i = j ? ld[0][0].w : ld[0][0].y;
        float w1r = j ? ld[1][0].z : ld[1][0].x;
        float w1i = j ? ld[1][0].w : ld[1][0].y;
        float v0r = j ? ld[0][1].z : ld[0][1].x;
        float v0i = j ? ld[0][1].w : ld[0][1].y;
        float v1r = j ? ld[1][1].z : ld[1][1].x;
        float v1i = j ? ld[1][1].w : ld[1][1].y;
        float zr0 = fmaf(P.x, w0r, fmaf(-P.y, w0i, fmaf(P.z, w1r, fmaf(-P.w, w1i, Bb.x))));
        float zi0 = fmaf(P.y, w0r, fmaf( P.x, w0i, fmaf(P.w, w1r, fmaf( P.z, w1i, Bb.y))));
        float zr1 = fmaf(Q.x, v0r, fmaf(-Q.y, v0i, fmaf(Q.z, v1r, fmaf(-Q.w, v1i, Bb.z))));
        float zi1 = fmaf(Q.y, v0r, fmaf( Q.x, v0i, fmaf(Q.w, v1r, fmaf( Q.z, v1i, Bb.w))));
        float d2 = fmaxf(fmaf(zr1, zr1, zi1 * zi1), 1e-12f);
        float rn = __builtin_amdgcn_rsqf(d2);          // v_rsq_f32, ~1 ulp
        wf[b][k][j] = fmaf(zr0, zr1, zi0 * zi1) * rn;
      }
    }
  }

  // ---- phase B: gram[4][36] + S[4][8] reduction (2-px register pre-sum) ----
  int lane = t & 63, wv = t >> 6;
#pragma unroll
  for (int b = 0; b < BATCH; ++b) {
    int idx = b * 36;
#pragma unroll
    for (int r = 0; r < RANK; ++r)
#pragma unroll
      for (int s2 = r; s2 < RANK; ++s2, ++idx) {
        float pr = dpp_sum64(fmaf(wf[b][r][0], wf[b][s2][0], wf[b][r][1] * wf[b][s2][1]));
        if (lane == 63) gred[wv][idx] = pr;
      }
  }
#pragma unroll
  for (int b = 0; b < BATCH; ++b)
#pragma unroll
    for (int k = 0; k < RANK; ++k) {
      float pr = dpp_sum64(wf[b][k][0] + wf[b][k][1]);
      if (lane == 63) gred[wv][144 + b * 8 + k] = pr;
    }

  // ---- stash wf in LDS (frees all 64 persistent VGPRs across the barrier) --
#pragma unroll
  for (int b = 0; b < BATCH; ++b)
#pragma unroll
    for (int k = 0; k < RANK; ++k) {
      wfl[(((b * 8 + k) * 2 + 0) << 8) | t] = wf[b][k][0];
      wfl[(((b * 8 + k) * 2 + 1) << 8) | t] = wf[b][k][1];
    }

  __syncthreads();
  for (int i = t; i < NACC; i += 256) {
    float s = gred[0][i] + gred[1][i] + gred[2][i] + gred[3][i];
    // 8-way replicated accumulators: same-address contention /8
    atomicAdd(ws + ACC_OFF + (blockIdx.x & (REP - 1)) * NACC + i, s);
  }

  // ---- device-scope grid barrier (512 blocks co-resident: LDS-pinned) -----
  __syncthreads();
  if (t == 0) {
    unsigned int* bar = (unsigned int*)ws + BAR_IDX;
    __hip_atomic_fetch_add(bar, 1u, __ATOMIC_ACQ_REL, __HIP_MEMORY_SCOPE_AGENT);
    while (__hip_atomic_load(bar, __ATOMIC_ACQUIRE, __HIP_MEMORY_SCOPE_AGENT) < (unsigned int)NBLK)
      __builtin_amdgcn_s_sleep(1);
  }
  __syncthreads();

  // ---- phase D: analytic stats (redundant per block; trivial ALU) ----------
  if (t < NACC) {
    float s = 0.f;
#pragma unroll
    for (int rep = 0; rep < REP; ++rep)
      s += __hip_atomic_load(ws + ACC_OFF + rep * NACC + t,
                             __ATOMIC_RELAXED, __HIP_MEMORY_SCOPE_AGENT);
    G[t] = s;
  }
  if (t >= 192 && t < 192 + BATCH) {         // wr softmax (per-batch thread)
    int b = t - 192;
    float raw[9];
#pragma unroll
    for (int j = 0; j < 9; ++j)
      raw[j] = xt[b * OUTF + 96 + j] * tanhf(xt[b * OUTF + 201 + j]);
    raw[8] += 0.35355339059327373f;          // 1/sqrt(8)
    double ss = 0.0;
#pragma unroll
    for (int j = 0; j < 9; ++j) ss += (double)raw[j] * (double)raw[j];
    float n = fmaxf((float)sqrt(ss), 1e-12f);
    float y[9]; float m = -1e30f;
#pragma unroll
    for (int j = 0; j < 9; ++j) { y[j] = raw[j] / n; m = fmaxf(m, y[j]); }
    float e[9]; double se = 0.0;
#pragma unroll
    for (int j = 0; j < 9; ++j) { e[j] = expf(y[j] - m); se += (double)e[j]; }
#pragma unroll
    for (int j = 0; j < 9; ++j) wrl[b][j] = e[j] / (float)se;
  }
  __syncthreads();
  if (t < 32) {
    int b = t >> 3, k = t & 7;
    int di = k * 8 - (k * (k - 1)) / 2;
    n1[t] = fmaxf(sqrtf(G[b * 36 + di]), 1e-12f);
  }
  __syncthreads();
  {
    int b = t >> 6, k = (t >> 3) & 7, s = t & 7;
    float m;
    if (k == s) {
      m = 1.0f / n1[b * 8 + k];
    } else {
      int r0 = k < s ? k : s, s0 = k < s ? s : k;
      int gi = r0 * 8 - (r0 * (r0 - 1)) / 2 + (s0 - r0);
      float simv = G[b * 36 + gi] / (n1[b * 8 + k] * n1[b * 8 + s]);
      m = -0.0050507627227610544f * simv / n1[b * 8 + s];  // (0.1/sqrt(8))/7
    }
    Ml[t] = m;
  }
  __syncthreads();
  if (t < 32) {
    int b = t >> 3, k = t & 7;
    // sum = M.S ; sumsq = (M G M^T)_kk — exact linear algebra of the 2nd pass
    float sum = 0.f, sq = 0.f;
#pragma unroll
    for (int s = 0; s < 8; ++s) {
      float ms = Ml[b * 64 + k * 8 + s];
      sum = fmaf(ms, G[144 + b * 8 + s], sum);
#pragma unroll
      for (int u = 0; u < 8; ++u) {
        int r0 = s < u ? s : u, s0 = s < u ? u : s;
        int gi = r0 * 8 - (r0 * (r0 - 1)) / 2 + (s0 - r0);
        sq = fmaf(ms * Ml[b * 64 + k * 8 + u], G[b * 36 + gi], sq);
      }
    }
    float n2 = fmaxf(sqrtf(fmaxf(sq, 0.f)), 1e-12f);
    float mean = sum / n2 * (1.0f / NPIX);
    float sy2 = sq / (n2 * n2);
    float var = (sy2 - (float)NPIX * mean * mean) * (1.0f / (float)(NPIX - 1));
    var = fmaxf(var, 0.f);
    float sd = fmaxf(sqrtf(var), 1e-12f);
    in2[t] = 1.f / n2; mnv[t] = mean; sdv[t] = sd;
  }
  __syncthreads();
  if (t < 32) {
    int b = t >> 3, s = t & 7;
    float acc = 0.f;
#pragma unroll
    for (int k = 0; k < 8; ++k)
      acc += wrl[b][k] * Ml[b * 64 + k * 8 + s] * in2[b * 8 + k];
    vv[t] = acc;
    scl[t] = wrl[b][s] * 0.01f * sdv[t];
  }
  if (t < BATCH) {
    float a = 0.f;
#pragma unroll
    for (int k = 0; k < 8; ++k) a += wrl[t][k] * 0.01f * mnv[t * 8 + k];
    ca[t] = a;
  }
  __syncthreads();

  // ---- phase E: output from LDS-staged wf + noise folded in on the fly -----
  float o0[4], o1[4];
#pragma unroll
  for (int b = 0; b < 4; ++b) { o0[b] = ca[b]; o1[b] = ca[b]; }
#pragma unroll
  for (int b = 0; b < 4; ++b)
#pragma unroll
    for (int s = 0; s < 8; ++s) {
      float v = vv[b * 8 + s];
      o0[b] = fmaf(v, wfl[(((b * 8 + s) * 2 + 0) << 8) | t], o0[b]);
      o1[b] = fmaf(v, wfl[(((b * 8 + s) * 2 + 1) << 8) | t], o1[b]);
    }
  // noise: flat j=(b*8+k)*NPIX+px over 2^23 elems; (j, j+2^22) share a block
#pragma unroll
  for (int bk = 0; bk < 16; ++bk) {
    unsigned int i0 = ((unsigned int)bk << 18) + 2u * (unsigned int)tp;
    unsigned int ra0, ra1, rb0, rb1;
    threefry2x32_pair(i0,      i0 + 0x400000u, &ra0, &ra1);
    threefry2x32_pair(i0 + 1u, i0 + 0x400001u, &rb0, &rb1);
    int b2 = bk >> 3, k = bk & 7;
    o0[b2]     = fmaf(scl[b2 * 8 + k],       fast_normal(ra0), o0[b2]);
    o1[b2]     = fmaf(scl[b2 * 8 + k],       fast_normal(rb0), o1[b2]);
    o0[b2 + 2] = fmaf(scl[(b2 + 2) * 8 + k], fast_normal(ra1), o0[b2 + 2]);
    o1[b2 + 2] = fmaf(scl[(b2 + 2) * 8 + k], fast_normal(rb1), o1[b2 + 2]);
  }
#pragma unroll
  for (int b = 0; b < 4; ++b)
    ((float2*)out)[(b << 17) + tp] = make_float2(o0[b], o1[b]);  // coalesced 8B
}

extern "C" void kernel_launch(void* const* d_in, const int* in_sizes, int n_in,
                              void* d_out, int out_size, void* d_ws, size_t ws_size,
                              hipStream_t stream) {
  const float* x   = (const float*)d_in[0];
  const float* cw  = (const float*)d_in[1];
  const float* cb  = (const float*)d_in[2];
  const float* wts = (const float*)d_in[3];
  float* out = (float*)d_out;
  float* ws  = (float*)d_ws;

  k_ctx  <<<210,  256, 0,         stream>>>(x, cw, cb, ws);   // xt + zero ACC/bar
  k_fused<<<NBLK, 256, WFL_BYTES, stream>>>(wts, ws, out);    // everything else
}